// Round 4
// baseline (357.069 us; speedup 1.0000x reference)
//
#include <hip/hip_runtime.h>

typedef unsigned long long u64;
typedef unsigned int u32;

#define KLVL 300
#define NPROP 900
#define MAXPROP 500
#define DDIM 213
#define EDIM 208

// anchors_px / stride (all exact in binary: /8,/16,/32)
__constant__ float c_anc[3][4][2] = {
  {{1.0f, 3.0f}, {1.375f, 4.25f}, {2.0f, 6.0f}, {2.875f, 8.5f}},
  {{2.0f, 6.0f}, {2.8125f, 8.4375f}, {4.0f, 12.0f}, {5.625f, 16.9375f}},
  {{4.0f, 12.0f}, {5.625f, 16.875f}, {8.0f, 20.0f}, {16.0f, 20.0f}},
};
__constant__ float c_scale[3] = { (float)(8.0 / 608.0), (float)(16.0 / 608.0), (float)(32.0 / 608.0) };

__device__ __forceinline__ int level_H(int lvl) { return (lvl == 0) ? 76 : ((lvl == 1) ? 38 : 19); }

// ---------------- workspace layout (bytes) ----------------
#define SB_STRIDE 30336            // per-image score stride (elems)
#define MASKT_STRIDE 904           // u64 per word-column (rows padded to 904)
#define MASK_IMG (15*904)          // 13560 u64 per image
#define BOX_STRIDE 928
#define BOX_IMG (6*928)            // x1,y1,x2,y2,sc,slot

#define OFF_SCORES 0               // 16*30336*4 = 1,941,504 ; mask_T aliases (1,735,680) after collect
#define OFF_HIST   1945600         // 48*2048*4 = 393,216 ; bufT aliases after thresh
#define OFF_BUFTS  1945600         // 48*1024*4 = 196,608
#define OFF_BUFTI  2142208         // 196,608
#define OFF_BUFGS  2338816         // 48*512*4 = 98,304
#define OFF_BUFGI  2437120         // 98,304
#define OFF_CNTG   2535424
#define OFF_CNTT   2535680
#define OFF_THR    2535936
#define OFF_CNT    2536192
#define OFF_SELS   2536448         // 16*900*4
#define OFF_SELI   2594048         // 16*900*4
#define OFF_BOX    2651904         // 16*6*928*4 = 356,352
#define OFF_SRC    3008256         // 16*500*4 = 32,000 -> end 3,040,256

__device__ __forceinline__ u64 readlane_u64(u64 v, int l) {
  u32 lo = (u32)__builtin_amdgcn_readlane((int)(u32)(v & 0xFFFFFFFFull), l);
  u32 hi = (u32)__builtin_amdgcn_readlane((int)(u32)(v >> 32), l);
  return ((u64)hi << 32) | (u64)lo;
}

// ---------------------------------------------------------------------------
// Kernel 0: zero the histogram region (graph-capture-safe init)
// ---------------------------------------------------------------------------
__global__ __launch_bounds__(1024) void zero_kernel(u32* __restrict__ h) {
  h[blockIdx.x * 1024 + threadIdx.x] = 0u;   // grid 96 x 1024 == 98,304 words exactly
}

// ---------------------------------------------------------------------------
// Kernel 1: conf scores for ALL anchors + global 2048-bucket histogram
// grid = 16*120, block = 256
// ---------------------------------------------------------------------------
__global__ __launch_bounds__(256) void score_kernel(
    const float* __restrict__ pred0, const float* __restrict__ pred1, const float* __restrict__ pred2,
    float* __restrict__ ws_scores, u32* __restrict__ hist)
{
  const int blk = blockIdx.x;
  const int b = blk / 120;
  const int r = blk % 120;
  int lvl, rb, N, off;
  const float* pred;
  if (r < 91)       { lvl = 0; rb = r;       N = 23104; off = 0;     pred = pred0; }
  else if (r < 114) { lvl = 1; rb = r - 91;  N = 5776;  off = 23104; pred = pred1; }
  else              { lvl = 2; rb = r - 114; N = 1444;  off = 28880; pred = pred2; }
  const int n = rb * 256 + (int)threadIdx.x;
  if (n >= N) return;
  const float* pb = pred + (size_t)b * N * 6;
  float2 l = *reinterpret_cast<const float2*>(pb + (size_t)n * 6 + 4);
  float m = fmaxf(l.x, l.y);
  float e0 = expf(l.x - m), e1 = expf(l.y - m);
  float s = e1 / (e0 + e1);
  float sm = (s > 0.5f) ? s : 0.0f;
  ws_scores[(size_t)b * SB_STRIDE + off + n] = sm;
  if (sm > 0.0f) {
    u32 key = __float_as_uint(sm) - 0x3F000000u;
    u32 bk = min(key >> 12, 2047u);
    atomicAdd(&hist[(u32)(b * 3 + lvl) * 2048u + bk], 1u);
  }
}

// ---------------------------------------------------------------------------
// Kernel 2: per-(b,lvl) threshold bucket from histogram
// grid = 48, block = 256
// ---------------------------------------------------------------------------
__global__ __launch_bounds__(256) void thresh_kernel(
    const u32* __restrict__ hist, int* __restrict__ thrT, int* __restrict__ cnt,
    u32* __restrict__ cntG, u32* __restrict__ cntT)
{
  __shared__ u32 wt[4];
  __shared__ int sT;
  const int bl = blockIdx.x, t = threadIdx.x, lane = t & 63, wid = t >> 6;
  const u32* h = hist + (size_t)bl * 2048;
  u32 hv[8]; u32 part = 0;
  #pragma unroll
  for (int q = 0; q < 8; ++q) { hv[q] = h[2047 - 8 * t - q]; part += hv[q]; }
  u32 incl = part;
  #pragma unroll
  for (int off = 1; off < 64; off <<= 1) { u32 v = __shfl_up(incl, (unsigned)off, 64); if (lane >= off) incl += v; }
  if (lane == 63) wt[wid] = incl;
  __syncthreads();
  u32 above = 0;
  for (int w2 = 0; w2 < wid; ++w2) above += wt[w2];
  const u32 total = wt[0] + wt[1] + wt[2] + wt[3];
  if (total > 300u) {
    u32 run = above + incl - part;
    #pragma unroll
    for (int q = 0; q < 8; ++q) {
      u32 hq = hv[q];
      if (hq && run < 300u && 300u <= run + hq) sT = 2047 - 8 * t - q;
      run += hq;
    }
  }
  __syncthreads();
  if (t == 0) {
    thrT[bl] = (total <= 300u) ? -1 : sT;
    cnt[bl] = (int)min(total, 300u);
    cntG[bl] = 0u; cntT[bl] = 0u;
  }
}

// ---------------------------------------------------------------------------
// Kernel 3: collect strictly-greater-bucket items and tie-bucket items
// grid = 16*120, block = 256
// ---------------------------------------------------------------------------
__global__ __launch_bounds__(256) void collect_kernel(
    const float* __restrict__ ws_scores, const int* __restrict__ thrT,
    u32* __restrict__ cntG, u32* __restrict__ cntT,
    float* __restrict__ bufGs, int* __restrict__ bufGi,
    float* __restrict__ bufTs, int* __restrict__ bufTi)
{
  const int blk = blockIdx.x;
  const int b = blk / 120;
  const int r = blk % 120;
  int lvl, rb, N, off;
  if (r < 91)       { lvl = 0; rb = r;       N = 23104; off = 0;     }
  else if (r < 114) { lvl = 1; rb = r - 91;  N = 5776;  off = 23104; }
  else              { lvl = 2; rb = r - 114; N = 1444;  off = 28880; }
  const int n = rb * 256 + (int)threadIdx.x;
  if (n >= N) return;
  float s = ws_scores[(size_t)b * SB_STRIDE + off + n];
  if (s <= 0.0f) return;
  u32 key = __float_as_uint(s) - 0x3F000000u;
  int bk = (int)min(key >> 12, 2047u);
  const int bl = b * 3 + lvl;
  const int T = thrT[bl];
  if (bk > T) {
    u32 p = atomicAdd(&cntG[bl], 1u);
    if (p < 512u) { bufGs[bl * 512 + p] = s; bufGi[bl * 512 + p] = n; }
  } else if (bk == T) {
    u32 p = atomicAdd(&cntT[bl], 1u);
    if (p < 1024u) { bufTs[bl * 1024 + p] = s; bufTi[bl * 1024 + p] = n; }
  }
}

// ---------------------------------------------------------------------------
// Kernel 4: exact (score desc, idx asc) sort via rank-by-count -> sel arrays
// grid = 48, block = 1024
// ---------------------------------------------------------------------------
__global__ __launch_bounds__(1024) void sort_kernel(
    const float* __restrict__ bufGs, const int* __restrict__ bufGi,
    const float* __restrict__ bufTs, const int* __restrict__ bufTi,
    const u32* __restrict__ cntG, const u32* __restrict__ cntT, const int* __restrict__ cnt,
    float* __restrict__ sel_score, int* __restrict__ sel_idx)
{
  __shared__ float gs[512]; __shared__ int gi[512];
  __shared__ float ts[1024]; __shared__ int ti[1024];
  const int bl = blockIdx.x, t = threadIdx.x;
  const int b = bl / 3, lvl = bl % 3;
  const int G = (int)min(cntG[bl], 512u);
  const int Tn = (int)min(cntT[bl], 1024u);
  const int selCnt = cnt[bl];
  if (t < G) { gs[t] = bufGs[bl * 512 + t]; gi[t] = bufGi[bl * 512 + t]; }
  if (t < Tn) { ts[t] = bufTs[bl * 1024 + t]; ti[t] = bufTi[bl * 1024 + t]; }
  __syncthreads();
  float* out_s = sel_score + (size_t)b * NPROP + (size_t)lvl * KLVL;
  int* out_i = sel_idx + (size_t)b * NPROP + (size_t)lvl * KLVL;
  if (t < G) {
    float sv = gs[t]; int iv = gi[t];
    int rk = 0;
    for (int j = 0; j < G; ++j) { float sj = gs[j]; int ij = gi[j]; rk += ((sj > sv) || (sj == sv && ij < iv)) ? 1 : 0; }
    out_s[rk] = sv; out_i[rk] = iv;
  }
  if (t < Tn) {
    float sv = ts[t]; int iv = ti[t];
    int rk = 0;
    for (int j = 0; j < Tn; ++j) { float sj = ts[j]; int ij = ti[j]; rk += ((sj > sv) || (sj == sv && ij < iv)) ? 1 : 0; }
    if (rk < selCnt - G) { out_s[G + rk] = sv; out_i[G + rk] = iv; }
  }
  for (int s2 = selCnt + t; s2 < KLVL; s2 += 1024) { out_s[s2] = 0.0f; out_i[s2] = 0; }
}

// ---------------------------------------------------------------------------
// Kernel 5: global rank (3-way sorted merge) + box decode + transposed IoU mask
// grid = 16, block = 1024
// ---------------------------------------------------------------------------
__global__ __launch_bounds__(1024) void rankmask_kernel(
    const float* __restrict__ pred0, const float* __restrict__ pred1, const float* __restrict__ pred2,
    const float* __restrict__ sel_score, const int* __restrict__ sel_idx, const int* __restrict__ cnt,
    float* __restrict__ ws_box, u64* __restrict__ ws_mask)
{
  __shared__ float s_sc[NPROP];
  __shared__ int s_ix[NPROP];
  __shared__ int s_c[3];
  __shared__ float s_x1[904], s_y1[904], s_x2[904], s_y2[904], s_ar[904];
  const int b = blockIdx.x, t = threadIdx.x;
  if (t < 3) s_c[t] = cnt[b * 3 + t];
  if (t < NPROP) { s_sc[t] = sel_score[(size_t)b * NPROP + t]; s_ix[t] = sel_idx[(size_t)b * NPROP + t]; }
  __syncthreads();
  const int Np = s_c[0] + s_c[1] + s_c[2];
  if (t < NPROP) {
    int lvl = t / KLVL, pos = t - lvl * KLVL;
    if (pos < s_c[lvl]) {
      float sv = s_sc[t];
      u32 rank = (u32)pos;
      for (int ol = 0; ol < 3; ++ol) {
        if (ol == lvl) continue;
        int base = ol * KLVL, co = s_c[ol];
        int lo2 = 0, hi2 = co;
        if (ol < lvl) {
          while (lo2 < hi2) { int mid = (lo2 + hi2) >> 1; if (s_sc[base + mid] >= sv) lo2 = mid + 1; else hi2 = mid; }
        } else {
          while (lo2 < hi2) { int mid = (lo2 + hi2) >> 1; if (s_sc[base + mid] > sv) lo2 = mid + 1; else hi2 = mid; }
        }
        rank += (u32)lo2;
      }
      int n = s_ix[t];
      int Hl = level_H(lvl), HWl = Hl * Hl;
      int a = n / HWl, rem = n - a * HWl, gy = rem / Hl, gx = rem - gy * Hl;
      const float* pred = (lvl == 0) ? pred0 : ((lvl == 1) ? pred1 : pred2);
      const float* p = pred + ((size_t)b * 4 * HWl + (size_t)n) * 6;
      float p0 = p[0], p1 = p[1], p2 = p[2], p3 = p[3];
      float aw = c_anc[lvl][a][0], ah = c_anc[lvl][a][1];
      float x = p0 * aw + (float)gx;
      float y = p1 * ah + (float)gy;
      float wv = expf(p2) * aw;
      float hv = expf(p3) * ah;
      float sc = c_scale[lvl];
      float x1 = fminf(fmaxf((x - 0.5f * wv) * sc, 0.0f), 1.0f);
      float y1 = fminf(fmaxf((y - 0.5f * hv) * sc, 0.0f), 1.0f);
      float x2 = fminf(fmaxf((x + 0.5f * wv) * sc, 0.0f), 1.0f);
      float y2 = fminf(fmaxf((y + 0.5f * hv) * sc, 0.0f), 1.0f);
      float* Bx = ws_box + (size_t)b * BOX_IMG;
      Bx[rank] = x1;
      Bx[BOX_STRIDE + rank] = y1;
      Bx[2 * BOX_STRIDE + rank] = x2;
      Bx[3 * BOX_STRIDE + rank] = y2;
      Bx[4 * BOX_STRIDE + rank] = sv;
      ((int*)(Bx + 5 * BOX_STRIDE))[rank] = t;   // slot
      s_x1[rank] = x1; s_y1[rank] = y1; s_x2[rank] = x2; s_y2[rank] = y2;
      s_ar[rank] = (x2 - x1) * (y2 - y1);
    }
  }
  __syncthreads();
  // transposed suppression mask: mkT[w*904 + i], zero-padded to 904 rows
  u64* mkT = ws_mask + (size_t)b * MASK_IMG;
  const int nW = (Np + 63) >> 6;
  for (int task = t; task < 15 * 904; task += 1024) {
    int w = task / 904, i = task - w * 904;
    u64 bits = 0;
    if (i < Np && w < nW) {
      int j0 = w << 6;
      int jlim = min(64, Np - j0);
      if (j0 + 63 > i) {
        float xi1 = s_x1[i], yi1 = s_y1[i], xi2 = s_x2[i], yi2 = s_y2[i], ai = s_ar[i];
        for (int jj = 0; jj < jlim; ++jj) {
          int j = j0 + jj;
          if (j > i) {
            float xx1 = fmaxf(xi1, s_x1[j]);
            float yy1 = fmaxf(yi1, s_y1[j]);
            float xx2 = fminf(xi2, s_x2[j]);
            float yy2 = fminf(yi2, s_y2[j]);
            float iw = fmaxf(xx2 - xx1, 0.0f);
            float ih = fmaxf(yy2 - yy1, 0.0f);
            float inter = iw * ih;
            float iou = inter / (ai + s_ar[j] - inter + 1e-9f);
            if (iou > 0.45f) bits |= (1ull << jj);
          }
        }
      }
    }
    mkT[(size_t)w * MASKT_STRIDE + i] = bits;
  }
}

// ---------------------------------------------------------------------------
// Kernel 6: greedy NMS scan — serial chain in registers/SGPRs only
// grid = 16, block = 64 (one wave)
// ---------------------------------------------------------------------------
__global__ __launch_bounds__(64) void scan_kernel(
    const u64* __restrict__ ws_mask, const int* __restrict__ cnt, int* __restrict__ ws_src)
{
  __shared__ u64 s_keep[16];
  __shared__ u32 s_pre[16];
  const int b = blockIdx.x;
  const int lane = (int)threadIdx.x;
  const int Np = cnt[b * 3] + cnt[b * 3 + 1] + cnt[b * 3 + 2];
  const u64* mkT = ws_mask + (size_t)b * MASK_IMG;

  // diagonal 64x64 blocks: lane j holds row (c*64+j)'s word c (rows >= Np are zero-filled)
#define DECL_DIAG(c) u64 d##c = mkT[(size_t)(c) * MASKT_STRIDE + (c) * 64 + lane];
  DECL_DIAG(0) DECL_DIAG(1) DECL_DIAG(2) DECL_DIAG(3) DECL_DIAG(4)
  DECL_DIAG(5) DECL_DIAG(6) DECL_DIAG(7) DECL_DIAG(8) DECL_DIAG(9)
  DECL_DIAG(10) DECL_DIAG(11) DECL_DIAG(12) DECL_DIAG(13) DECL_DIAG(14)
#undef DECL_DIAG

  u64 remv = 0;   // lane w (<15): suppression word w accumulated from earlier tiles
  u64 keepw = 0;  // lane c (<15): keep word of tile c

#define TILE(c, dvar) \
  if ((c) * 64 < Np) { \
    u64 rv = readlane_u64(remv, (c)); \
    int rem_ = Np - (c) * 64; \
    u64 valid_ = (rem_ >= 64) ? ~0ull : ((1ull << rem_) - 1ull); \
    u64 live = valid_ & ~rv; \
    u64 keep = 0; \
    while (live) { \
      int j_ = (int)__builtin_ctzll(live); \
      keep |= (1ull << j_); \
      u64 row_ = readlane_u64(dvar, j_); \
      live &= ~(row_ | (1ull << j_)); \
    } \
    if (lane == (c)) keepw = keep; \
    if (keep && lane > (c) && lane < 15) { \
      const u64* colw_ = mkT + (size_t)lane * MASKT_STRIDE + (c) * 64; \
      u64 acc_ = 0; \
      _Pragma("unroll") \
      for (int ch_ = 0; ch_ < 8; ++ch_) { \
        u64 r0_ = colw_[ch_ * 8 + 0], r1_ = colw_[ch_ * 8 + 1], r2_ = colw_[ch_ * 8 + 2], r3_ = colw_[ch_ * 8 + 3]; \
        u64 r4_ = colw_[ch_ * 8 + 4], r5_ = colw_[ch_ * 8 + 5], r6_ = colw_[ch_ * 8 + 6], r7_ = colw_[ch_ * 8 + 7]; \
        u32 kb_ = (u32)((keep >> (ch_ * 8)) & 0xFFull); \
        acc_ |= (kb_ & 1u ? r0_ : 0) | (kb_ & 2u ? r1_ : 0) | (kb_ & 4u ? r2_ : 0) | (kb_ & 8u ? r3_ : 0) \
              | (kb_ & 16u ? r4_ : 0) | (kb_ & 32u ? r5_ : 0) | (kb_ & 64u ? r6_ : 0) | (kb_ & 128u ? r7_ : 0); \
      } \
      remv |= acc_; \
    } \
  }

  TILE(0, d0) TILE(1, d1) TILE(2, d2) TILE(3, d3) TILE(4, d4)
  TILE(5, d5) TILE(6, d6) TILE(7, d7) TILE(8, d8) TILE(9, d9)
  TILE(10, d10) TILE(11, d11) TILE(12, d12) TILE(13, d13) TILE(14, d14)
#undef TILE

  // keep words -> LDS + exclusive prefix of popcounts
  u32 pc = (lane < 15) ? (u32)__popcll(keepw) : 0u;
  u32 incl = pc;
  #pragma unroll
  for (int off = 1; off < 64; off <<= 1) { u32 v = __shfl_up(incl, (unsigned)off, 64); if (lane >= off) incl += v; }
  if (lane < 16) { s_keep[lane] = (lane < 15) ? keepw : 0ull; s_pre[lane] = incl - pc; }
  __syncthreads();

  int* src = ws_src + b * MAXPROP;
  for (int r = lane; r < MAXPROP; r += 64) src[r] = -1;
  for (int i = lane; i < Np; i += 64) {
    u64 kw = s_keep[i >> 6];
    if ((kw >> (i & 63)) & 1ull) {
      u32 rank = s_pre[i >> 6] + (u32)__popcll(kw & ((1ull << (i & 63)) - 1ull));
      if (rank < MAXPROP) src[rank] = i;
    }
  }
}

// ---------------------------------------------------------------------------
// Kernel 7: output rows — one wave per row
// grid = 2000, block = 256
// ---------------------------------------------------------------------------
__global__ __launch_bounds__(256) void out_kernel(
    const float* __restrict__ emb0, const float* __restrict__ emb1, const float* __restrict__ emb2,
    const float* __restrict__ ws_box, const int* __restrict__ ws_src, const int* __restrict__ sel_idx,
    float* __restrict__ out)
{
  const int blk = blockIdx.x;
  const int b = blk / 125;
  const int r = (blk % 125) * 4 + ((int)threadIdx.x >> 6);
  const int lane = (int)threadIdx.x & 63;
  float* orow = out + ((size_t)b * MAXPROP + r) * DDIM;
  const int i = ws_src[b * MAXPROP + r];
  if (i < 0) {
    for (int c = lane; c < DDIM; c += 64) orow[c] = 0.0f;
    return;
  }
  const float* B = ws_box + (size_t)b * BOX_IMG;
  float x1 = B[i], y1 = B[BOX_STRIDE + i], x2 = B[2 * BOX_STRIDE + i], y2 = B[3 * BOX_STRIDE + i];
  float score = B[4 * BOX_STRIDE + i];
  int slot = ((const int*)(B + 5 * BOX_STRIDE))[i];
  int n = sel_idx[(size_t)b * NPROP + slot];
  int lvl = slot / KLVL;
  int Hl = level_H(lvl), HWl = Hl * Hl;
  int a = n / HWl, rem = n - a * HWl, gy = rem / Hl, gx = rem - gy * Hl;
  (void)a;
  const float* emb = (lvl == 0) ? emb0 : ((lvl == 1) ? emb1 : emb2);
  const float* e = emb + ((size_t)(b * Hl + gy) * Hl + gx) * EDIM;
  float v0 = e[lane], v1 = e[lane + 64], v2 = e[lane + 128];
  float v3 = (lane < 16) ? e[lane + 192] : 0.0f;
  float ss = v0 * v0 + v1 * v1 + v2 * v2 + v3 * v3;
  for (int off = 32; off > 0; off >>= 1) ss += __shfl_xor(ss, off, 64);
  float rs = 1.0f / sqrtf(fmaxf(ss, 1e-12f));
  if (lane == 0) {
    orow[0] = x1; orow[1] = y1; orow[2] = x2; orow[3] = y2; orow[4] = score;
  }
  orow[5 + lane] = v0 * rs;
  orow[5 + 64 + lane] = v1 * rs;
  orow[5 + 128 + lane] = v2 * rs;
  if (lane < 16) orow[5 + 192 + lane] = v3 * rs;
}

// ---------------------------------------------------------------------------
extern "C" void kernel_launch(void* const* d_in, const int* in_sizes, int n_in,
                              void* d_out, int out_size, void* d_ws, size_t ws_size,
                              hipStream_t stream) {
  const float* pred[3] = {nullptr, nullptr, nullptr};
  const float* emb[3] = {nullptr, nullptr, nullptr};
  for (int i = 0; i < n_in; ++i) {
    const float* p = (const float*)d_in[i];
    switch (in_sizes[i]) {
      case 2217984:  pred[0] = p; break;
      case 554496:   pred[1] = p; break;
      case 138624:   pred[2] = p; break;
      case 19222528: emb[0] = p; break;
      case 4805632:  emb[1] = p; break;
      case 1201408:  emb[2] = p; break;
      default: break;
    }
  }
  char* ws = (char*)d_ws;
  float* ws_scores = (float*)(ws + OFF_SCORES);
  u64* ws_mask = (u64*)(ws + OFF_SCORES);     // aliases scores (scores dead after collect)
  u32* hist = (u32*)(ws + OFF_HIST);
  float* bufTs = (float*)(ws + OFF_BUFTS);    // aliases hist (hist dead after thresh)
  int* bufTi = (int*)(ws + OFF_BUFTI);
  float* bufGs = (float*)(ws + OFF_BUFGS);
  int* bufGi = (int*)(ws + OFF_BUFGI);
  u32* cntG = (u32*)(ws + OFF_CNTG);
  u32* cntT = (u32*)(ws + OFF_CNTT);
  int* thrT = (int*)(ws + OFF_THR);
  int* cnt = (int*)(ws + OFF_CNT);
  float* sel_score = (float*)(ws + OFF_SELS);
  int* sel_idx = (int*)(ws + OFF_SELI);
  float* ws_box = (float*)(ws + OFF_BOX);
  int* ws_src = (int*)(ws + OFF_SRC);

  zero_kernel<<<dim3(96), dim3(1024), 0, stream>>>(hist);
  score_kernel<<<dim3(1920), dim3(256), 0, stream>>>(pred[0], pred[1], pred[2], ws_scores, hist);
  thresh_kernel<<<dim3(48), dim3(256), 0, stream>>>(hist, thrT, cnt, cntG, cntT);
  collect_kernel<<<dim3(1920), dim3(256), 0, stream>>>(ws_scores, thrT, cntG, cntT, bufGs, bufGi, bufTs, bufTi);
  sort_kernel<<<dim3(48), dim3(1024), 0, stream>>>(bufGs, bufGi, bufTs, bufTi, cntG, cntT, cnt, sel_score, sel_idx);
  rankmask_kernel<<<dim3(16), dim3(1024), 0, stream>>>(pred[0], pred[1], pred[2], sel_score, sel_idx, cnt, ws_box, ws_mask);
  scan_kernel<<<dim3(16), dim3(64), 0, stream>>>(ws_mask, cnt, ws_src);
  out_kernel<<<dim3(2000), dim3(256), 0, stream>>>(emb[0], emb[1], emb[2], ws_box, ws_src, sel_idx, (float*)d_out);
}

// Round 5
// 295.783 us; speedup vs baseline: 1.2072x; 1.2072x over previous
//
#include <hip/hip_runtime.h>

typedef unsigned long long u64;
typedef unsigned int u32;

#define KLVL 300
#define NPROP 900
#define MAXPROP 500
#define DDIM 213
#define EDIM 208

// anchors_px / stride (all exact in binary: /8,/16,/32)
__constant__ float c_anc[3][4][2] = {
  {{1.0f, 3.0f}, {1.375f, 4.25f}, {2.0f, 6.0f}, {2.875f, 8.5f}},
  {{2.0f, 6.0f}, {2.8125f, 8.4375f}, {4.0f, 12.0f}, {5.625f, 16.9375f}},
  {{4.0f, 12.0f}, {5.625f, 16.875f}, {8.0f, 20.0f}, {16.0f, 20.0f}},
};
__constant__ float c_scale[3] = { (float)(8.0 / 608.0), (float)(16.0 / 608.0), (float)(32.0 / 608.0) };

__device__ __forceinline__ int level_H(int lvl) { return (lvl == 0) ? 76 : ((lvl == 1) ? 38 : 19); }

// ---------------- workspace layout (bytes) ----------------
#define SB_STRIDE 30336            // per-image score stride (elems)
#define MASKT_STRIDE 904           // u64 per word-column (rows padded to 904)
#define MASK_IMG (15*904)          // 13560 u64 per image
#define BOX_STRIDE 928
#define BOX_IMG (6*928)            // x1,y1,x2,y2,sc,slot

#define OFF_SCORES 0               // 16*30336*4 = 1,941,504 ; mask_T aliases after collect
#define OFF_HIST   1945600         // 48*2048*4 = 393,216 ; bufT aliases after thresh
#define OFF_BUFTS  1945600
#define OFF_BUFTI  2142208
#define OFF_BUFGS  2338816
#define OFF_BUFGI  2437120
#define OFF_CNTG   2535424
#define OFF_CNTT   2535680
#define OFF_THR    2535936
#define OFF_CNT    2536192
#define OFF_SELS   2536448         // 16*900*4
#define OFF_SELI   2594048
#define OFF_BOX    2651904         // 16*6*928*4 = 356,352
#define OFF_SRC    3008256         // 16*500*4 -> end 3,040,256

__device__ __forceinline__ u64 readlane_u64(u64 v, int l) {
  u32 lo = (u32)__builtin_amdgcn_readlane((int)(u32)(v & 0xFFFFFFFFull), l);
  u32 hi = (u32)__builtin_amdgcn_readlane((int)(u32)(v >> 32), l);
  return ((u64)hi << 32) | (u64)lo;
}

// ---------------------------------------------------------------------------
// Kernel 1: conf scores for ALL anchors + global 2048-bucket histogram
// grid = 16*120, block = 256
// ---------------------------------------------------------------------------
__global__ __launch_bounds__(256) void score_kernel(
    const float* __restrict__ pred0, const float* __restrict__ pred1, const float* __restrict__ pred2,
    float* __restrict__ ws_scores, u32* __restrict__ hist)
{
  const int blk = blockIdx.x;
  const int b = blk / 120;
  const int r = blk % 120;
  int lvl, rb, N, off;
  const float* pred;
  if (r < 91)       { lvl = 0; rb = r;       N = 23104; off = 0;     pred = pred0; }
  else if (r < 114) { lvl = 1; rb = r - 91;  N = 5776;  off = 23104; pred = pred1; }
  else              { lvl = 2; rb = r - 114; N = 1444;  off = 28880; pred = pred2; }
  const int n = rb * 256 + (int)threadIdx.x;
  if (n >= N) return;
  const float* pb = pred + (size_t)b * N * 6;
  float2 l = *reinterpret_cast<const float2*>(pb + (size_t)n * 6 + 4);
  float m = fmaxf(l.x, l.y);
  float e0 = expf(l.x - m), e1 = expf(l.y - m);
  float s = e1 / (e0 + e1);
  float sm = (s > 0.5f) ? s : 0.0f;
  ws_scores[(size_t)b * SB_STRIDE + off + n] = sm;
  if (sm > 0.0f) {
    u32 key = __float_as_uint(sm) - 0x3F000000u;
    u32 bk = min(key >> 12, 2047u);
    atomicAdd(&hist[(u32)(b * 3 + lvl) * 2048u + bk], 1u);
  }
}

// ---------------------------------------------------------------------------
// Kernel 2: per-(b,lvl) threshold bucket from histogram
// grid = 48, block = 256
// ---------------------------------------------------------------------------
__global__ __launch_bounds__(256) void thresh_kernel(
    const u32* __restrict__ hist, int* __restrict__ thrT, int* __restrict__ cnt,
    u32* __restrict__ cntG, u32* __restrict__ cntT)
{
  __shared__ u32 wt[4];
  __shared__ int sT;
  const int bl = blockIdx.x, t = threadIdx.x, lane = t & 63, wid = t >> 6;
  const u32* h = hist + (size_t)bl * 2048;
  u32 hv[8]; u32 part = 0;
  #pragma unroll
  for (int q = 0; q < 8; ++q) { hv[q] = h[2047 - 8 * t - q]; part += hv[q]; }
  u32 incl = part;
  #pragma unroll
  for (int off = 1; off < 64; off <<= 1) { u32 v = __shfl_up(incl, (unsigned)off, 64); if (lane >= off) incl += v; }
  if (lane == 63) wt[wid] = incl;
  __syncthreads();
  u32 above = 0;
  for (int w2 = 0; w2 < wid; ++w2) above += wt[w2];
  const u32 total = wt[0] + wt[1] + wt[2] + wt[3];
  if (total > 300u) {
    u32 run = above + incl - part;
    #pragma unroll
    for (int q = 0; q < 8; ++q) {
      u32 hq = hv[q];
      if (hq && run < 300u && 300u <= run + hq) sT = 2047 - 8 * t - q;
      run += hq;
    }
  }
  __syncthreads();
  if (t == 0) {
    thrT[bl] = (total <= 300u) ? -1 : sT;
    cnt[bl] = (int)min(total, 300u);
    cntG[bl] = 0u; cntT[bl] = 0u;
  }
}

// ---------------------------------------------------------------------------
// Kernel 3: collect strictly-greater-bucket items and tie-bucket items
// grid = 16*120, block = 256
// ---------------------------------------------------------------------------
__global__ __launch_bounds__(256) void collect_kernel(
    const float* __restrict__ ws_scores, const int* __restrict__ thrT,
    u32* __restrict__ cntG, u32* __restrict__ cntT,
    float* __restrict__ bufGs, int* __restrict__ bufGi,
    float* __restrict__ bufTs, int* __restrict__ bufTi)
{
  const int blk = blockIdx.x;
  const int b = blk / 120;
  const int r = blk % 120;
  int lvl, rb, N, off;
  if (r < 91)       { lvl = 0; rb = r;       N = 23104; off = 0;     }
  else if (r < 114) { lvl = 1; rb = r - 91;  N = 5776;  off = 23104; }
  else              { lvl = 2; rb = r - 114; N = 1444;  off = 28880; }
  const int n = rb * 256 + (int)threadIdx.x;
  if (n >= N) return;
  float s = ws_scores[(size_t)b * SB_STRIDE + off + n];
  if (s <= 0.0f) return;
  u32 key = __float_as_uint(s) - 0x3F000000u;
  int bk = (int)min(key >> 12, 2047u);
  const int bl = b * 3 + lvl;
  const int T = thrT[bl];
  if (bk > T) {
    u32 p = atomicAdd(&cntG[bl], 1u);
    if (p < 512u) { bufGs[bl * 512 + p] = s; bufGi[bl * 512 + p] = n; }
  } else if (bk == T) {
    u32 p = atomicAdd(&cntT[bl], 1u);
    if (p < 1024u) { bufTs[bl * 1024 + p] = s; bufTi[bl * 1024 + p] = n; }
  }
}

// ---------------------------------------------------------------------------
// Kernel 4: exact (score desc, idx asc) sort via rank-by-count -> sel arrays
// grid = 48, block = 1024
// ---------------------------------------------------------------------------
__global__ __launch_bounds__(1024) void sort_kernel(
    const float* __restrict__ bufGs, const int* __restrict__ bufGi,
    const float* __restrict__ bufTs, const int* __restrict__ bufTi,
    const u32* __restrict__ cntG, const u32* __restrict__ cntT, const int* __restrict__ cnt,
    float* __restrict__ sel_score, int* __restrict__ sel_idx)
{
  __shared__ float gs[512]; __shared__ int gi[512];
  __shared__ float ts[1024]; __shared__ int ti[1024];
  const int bl = blockIdx.x, t = threadIdx.x;
  const int b = bl / 3, lvl = bl % 3;
  const int G = (int)min(cntG[bl], 512u);
  const int Tn = (int)min(cntT[bl], 1024u);
  const int selCnt = cnt[bl];
  if (t < G) { gs[t] = bufGs[bl * 512 + t]; gi[t] = bufGi[bl * 512 + t]; }
  if (t < Tn) { ts[t] = bufTs[bl * 1024 + t]; ti[t] = bufTi[bl * 1024 + t]; }
  __syncthreads();
  float* out_s = sel_score + (size_t)b * NPROP + (size_t)lvl * KLVL;
  int* out_i = sel_idx + (size_t)b * NPROP + (size_t)lvl * KLVL;
  if (t < G) {
    float sv = gs[t]; int iv = gi[t];
    int rk = 0;
    for (int j = 0; j < G; ++j) { float sj = gs[j]; int ij = gi[j]; rk += ((sj > sv) || (sj == sv && ij < iv)) ? 1 : 0; }
    out_s[rk] = sv; out_i[rk] = iv;
  }
  if (t < Tn) {
    float sv = ts[t]; int iv = ti[t];
    int rk = 0;
    for (int j = 0; j < Tn; ++j) { float sj = ts[j]; int ij = ti[j]; rk += ((sj > sv) || (sj == sv && ij < iv)) ? 1 : 0; }
    if (rk < selCnt - G) { out_s[G + rk] = sv; out_i[G + rk] = iv; }
  }
  for (int s2 = selCnt + t; s2 < KLVL; s2 += 1024) { out_s[s2] = 0.0f; out_i[s2] = 0; }
}

// ---------------------------------------------------------------------------
// Kernel 5: global rank (3-way sorted merge) + box decode
// grid = 48 (one per (b,lvl)), block = 512
// ---------------------------------------------------------------------------
__global__ __launch_bounds__(512) void rank_kernel(
    const float* __restrict__ pred0, const float* __restrict__ pred1, const float* __restrict__ pred2,
    const float* __restrict__ sel_score, const int* __restrict__ sel_idx, const int* __restrict__ cnt,
    float* __restrict__ ws_box)
{
  __shared__ float s_sc[NPROP];
  __shared__ int s_c[3];
  const int bl = blockIdx.x, t = threadIdx.x;
  const int b = bl / 3, lvl = bl % 3;
  if (t < 3) s_c[t] = cnt[b * 3 + t];
  for (int i = t; i < NPROP; i += 512) s_sc[i] = sel_score[(size_t)b * NPROP + i];
  __syncthreads();
  const int pos = t;
  if (pos < s_c[lvl]) {
    const int slot = lvl * KLVL + pos;
    float sv = s_sc[slot];
    u32 rank = (u32)pos;
    for (int ol = 0; ol < 3; ++ol) {
      if (ol == lvl) continue;
      int base = ol * KLVL, co = s_c[ol];
      int lo2 = 0, hi2 = co;
      if (ol < lvl) {  // earlier level: equal score ranks before me (count >=)
        while (lo2 < hi2) { int mid = (lo2 + hi2) >> 1; if (s_sc[base + mid] >= sv) lo2 = mid + 1; else hi2 = mid; }
      } else {         // later level: only strictly greater
        while (lo2 < hi2) { int mid = (lo2 + hi2) >> 1; if (s_sc[base + mid] > sv) lo2 = mid + 1; else hi2 = mid; }
      }
      rank += (u32)lo2;
    }
    int n = sel_idx[(size_t)b * NPROP + slot];
    int Hl = level_H(lvl), HWl = Hl * Hl;
    int a = n / HWl, rem = n - a * HWl, gy = rem / Hl, gx = rem - gy * Hl;
    const float* pred = (lvl == 0) ? pred0 : ((lvl == 1) ? pred1 : pred2);
    const float* p = pred + ((size_t)b * 4 * HWl + (size_t)n) * 6;
    float p0 = p[0], p1 = p[1], p2 = p[2], p3 = p[3];
    float aw = c_anc[lvl][a][0], ah = c_anc[lvl][a][1];
    float x = p0 * aw + (float)gx;
    float y = p1 * ah + (float)gy;
    float wv = expf(p2) * aw;
    float hv = expf(p3) * ah;
    float sc = c_scale[lvl];
    float x1 = fminf(fmaxf((x - 0.5f * wv) * sc, 0.0f), 1.0f);
    float y1 = fminf(fmaxf((y - 0.5f * hv) * sc, 0.0f), 1.0f);
    float x2 = fminf(fmaxf((x + 0.5f * wv) * sc, 0.0f), 1.0f);
    float y2 = fminf(fmaxf((y + 0.5f * hv) * sc, 0.0f), 1.0f);
    float* Bx = ws_box + (size_t)b * BOX_IMG;
    Bx[rank] = x1;
    Bx[BOX_STRIDE + rank] = y1;
    Bx[2 * BOX_STRIDE + rank] = x2;
    Bx[3 * BOX_STRIDE + rank] = y2;
    Bx[4 * BOX_STRIDE + rank] = sv;
    ((int*)(Bx + 5 * BOX_STRIDE))[rank] = slot;
  }
}

// ---------------------------------------------------------------------------
// Kernel 6: transposed IoU suppression mask, spread over (word w, image b)
// grid = (15, 16), block = 256; writes full zero-padded 904 rows per column
// ---------------------------------------------------------------------------
__global__ __launch_bounds__(256) void mask_kernel(
    const float* __restrict__ ws_box, const int* __restrict__ cnt, u64* __restrict__ ws_mask)
{
  const int w = blockIdx.x, b = blockIdx.y, t = threadIdx.x;
  const float* B = ws_box + (size_t)b * BOX_IMG;
  const float* X1 = B, * Y1 = B + BOX_STRIDE, * X2 = B + 2 * BOX_STRIDE, * Y2 = B + 3 * BOX_STRIDE;
  const int Np = cnt[b * 3] + cnt[b * 3 + 1] + cnt[b * 3 + 2];
  __shared__ float jx1[64], jy1[64], jx2[64], jy2[64], jar[64];
  if (t < 64) {
    int j = w * 64 + t;
    if (j < Np) {
      float a1 = X1[j], b1 = Y1[j], a2 = X2[j], b2 = Y2[j];
      jx1[t] = a1; jy1[t] = b1; jx2[t] = a2; jy2[t] = b2;
      jar[t] = (a2 - a1) * (b2 - b1);
    }
  }
  __syncthreads();
  u64* mkT = ws_mask + (size_t)b * MASK_IMG + (size_t)w * MASKT_STRIDE;
  const int j0 = w << 6;
  const int jlim = min(64, Np - j0);
  for (int i = t; i < 904; i += 256) {
    u64 bits = 0;
    if (i < Np && jlim > 0 && j0 + 63 > i) {
      float xi1 = X1[i], yi1 = Y1[i], xi2 = X2[i], yi2 = Y2[i];
      float ai = (xi2 - xi1) * (yi2 - yi1);
      for (int jj = 0; jj < jlim; ++jj) {
        int j = j0 + jj;
        if (j > i) {
          float xx1 = fmaxf(xi1, jx1[jj]);
          float yy1 = fmaxf(yi1, jy1[jj]);
          float xx2 = fminf(xi2, jx2[jj]);
          float yy2 = fminf(yi2, jy2[jj]);
          float iw = fmaxf(xx2 - xx1, 0.0f);
          float ih = fmaxf(yy2 - yy1, 0.0f);
          float inter = iw * ih;
          float iou = inter / (ai + jar[jj] - inter + 1e-9f);
          if (iou > 0.45f) bits |= (1ull << jj);
        }
      }
    }
    mkT[i] = bits;
  }
}

// ---------------------------------------------------------------------------
// Kernel 7: greedy NMS scan — serial chain in registers/SGPRs only
// grid = 16, block = 64 (one wave)
// ---------------------------------------------------------------------------
__global__ __launch_bounds__(64) void scan_kernel(
    const u64* __restrict__ ws_mask, const int* __restrict__ cnt, int* __restrict__ ws_src)
{
  __shared__ u64 s_keep[16];
  __shared__ u32 s_pre[16];
  const int b = blockIdx.x;
  const int lane = (int)threadIdx.x;
  const int Np = cnt[b * 3] + cnt[b * 3 + 1] + cnt[b * 3 + 2];
  const u64* mkT = ws_mask + (size_t)b * MASK_IMG;

#define DECL_DIAG(c) u64 d##c = mkT[(size_t)(c) * MASKT_STRIDE + (c) * 64 + lane];
  DECL_DIAG(0) DECL_DIAG(1) DECL_DIAG(2) DECL_DIAG(3) DECL_DIAG(4)
  DECL_DIAG(5) DECL_DIAG(6) DECL_DIAG(7) DECL_DIAG(8) DECL_DIAG(9)
  DECL_DIAG(10) DECL_DIAG(11) DECL_DIAG(12) DECL_DIAG(13) DECL_DIAG(14)
#undef DECL_DIAG

  u64 remv = 0;
  u64 keepw = 0;

#define TILE(c, dvar) \
  if ((c) * 64 < Np) { \
    u64 rv = readlane_u64(remv, (c)); \
    int rem_ = Np - (c) * 64; \
    u64 valid_ = (rem_ >= 64) ? ~0ull : ((1ull << rem_) - 1ull); \
    u64 live = valid_ & ~rv; \
    u64 keep = 0; \
    while (live) { \
      int j_ = (int)__builtin_ctzll(live); \
      keep |= (1ull << j_); \
      u64 row_ = readlane_u64(dvar, j_); \
      live &= ~(row_ | (1ull << j_)); \
    } \
    if (lane == (c)) keepw = keep; \
    if (keep && lane > (c) && lane < 15) { \
      const u64* colw_ = mkT + (size_t)lane * MASKT_STRIDE + (c) * 64; \
      u64 acc_ = 0; \
      _Pragma("unroll") \
      for (int ch_ = 0; ch_ < 8; ++ch_) { \
        u64 r0_ = colw_[ch_ * 8 + 0], r1_ = colw_[ch_ * 8 + 1], r2_ = colw_[ch_ * 8 + 2], r3_ = colw_[ch_ * 8 + 3]; \
        u64 r4_ = colw_[ch_ * 8 + 4], r5_ = colw_[ch_ * 8 + 5], r6_ = colw_[ch_ * 8 + 6], r7_ = colw_[ch_ * 8 + 7]; \
        u32 kb_ = (u32)((keep >> (ch_ * 8)) & 0xFFull); \
        acc_ |= (kb_ & 1u ? r0_ : 0) | (kb_ & 2u ? r1_ : 0) | (kb_ & 4u ? r2_ : 0) | (kb_ & 8u ? r3_ : 0) \
              | (kb_ & 16u ? r4_ : 0) | (kb_ & 32u ? r5_ : 0) | (kb_ & 64u ? r6_ : 0) | (kb_ & 128u ? r7_ : 0); \
      } \
      remv |= acc_; \
    } \
  }

  TILE(0, d0) TILE(1, d1) TILE(2, d2) TILE(3, d3) TILE(4, d4)
  TILE(5, d5) TILE(6, d6) TILE(7, d7) TILE(8, d8) TILE(9, d9)
  TILE(10, d10) TILE(11, d11) TILE(12, d12) TILE(13, d13) TILE(14, d14)
#undef TILE

  u32 pc = (lane < 15) ? (u32)__popcll(keepw) : 0u;
  u32 incl = pc;
  #pragma unroll
  for (int off = 1; off < 64; off <<= 1) { u32 v = __shfl_up(incl, (unsigned)off, 64); if (lane >= off) incl += v; }
  if (lane < 16) { s_keep[lane] = (lane < 15) ? keepw : 0ull; s_pre[lane] = incl - pc; }
  __syncthreads();

  int* src = ws_src + b * MAXPROP;
  for (int r = lane; r < MAXPROP; r += 64) src[r] = -1;
  for (int i = lane; i < Np; i += 64) {
    u64 kw = s_keep[i >> 6];
    if ((kw >> (i & 63)) & 1ull) {
      u32 rank = s_pre[i >> 6] + (u32)__popcll(kw & ((1ull << (i & 63)) - 1ull));
      if (rank < MAXPROP) src[rank] = i;
    }
  }
}

// ---------------------------------------------------------------------------
// Kernel 8: output rows — one wave per row
// grid = 2000, block = 256
// ---------------------------------------------------------------------------
__global__ __launch_bounds__(256) void out_kernel(
    const float* __restrict__ emb0, const float* __restrict__ emb1, const float* __restrict__ emb2,
    const float* __restrict__ ws_box, const int* __restrict__ ws_src, const int* __restrict__ sel_idx,
    float* __restrict__ out)
{
  const int blk = blockIdx.x;
  const int b = blk / 125;
  const int r = (blk % 125) * 4 + ((int)threadIdx.x >> 6);
  const int lane = (int)threadIdx.x & 63;
  float* orow = out + ((size_t)b * MAXPROP + r) * DDIM;
  const int i = ws_src[b * MAXPROP + r];
  if (i < 0) {
    for (int c = lane; c < DDIM; c += 64) orow[c] = 0.0f;
    return;
  }
  const float* B = ws_box + (size_t)b * BOX_IMG;
  float x1 = B[i], y1 = B[BOX_STRIDE + i], x2 = B[2 * BOX_STRIDE + i], y2 = B[3 * BOX_STRIDE + i];
  float score = B[4 * BOX_STRIDE + i];
  int slot = ((const int*)(B + 5 * BOX_STRIDE))[i];
  int n = sel_idx[(size_t)b * NPROP + slot];
  int lvl = slot / KLVL;
  int Hl = level_H(lvl), HWl = Hl * Hl;
  int a = n / HWl, rem = n - a * HWl, gy = rem / Hl, gx = rem - gy * Hl;
  (void)a;
  const float* emb = (lvl == 0) ? emb0 : ((lvl == 1) ? emb1 : emb2);
  const float* e = emb + ((size_t)(b * Hl + gy) * Hl + gx) * EDIM;
  float v0 = e[lane], v1 = e[lane + 64], v2 = e[lane + 128];
  float v3 = (lane < 16) ? e[lane + 192] : 0.0f;
  float ss = v0 * v0 + v1 * v1 + v2 * v2 + v3 * v3;
  for (int off = 32; off > 0; off >>= 1) ss += __shfl_xor(ss, off, 64);
  float rs = 1.0f / sqrtf(fmaxf(ss, 1e-12f));
  if (lane == 0) {
    orow[0] = x1; orow[1] = y1; orow[2] = x2; orow[3] = y2; orow[4] = score;
  }
  orow[5 + lane] = v0 * rs;
  orow[5 + 64 + lane] = v1 * rs;
  orow[5 + 128 + lane] = v2 * rs;
  if (lane < 16) orow[5 + 192 + lane] = v3 * rs;
}

// ---------------------------------------------------------------------------
extern "C" void kernel_launch(void* const* d_in, const int* in_sizes, int n_in,
                              void* d_out, int out_size, void* d_ws, size_t ws_size,
                              hipStream_t stream) {
  const float* pred[3] = {nullptr, nullptr, nullptr};
  const float* emb[3] = {nullptr, nullptr, nullptr};
  for (int i = 0; i < n_in; ++i) {
    const float* p = (const float*)d_in[i];
    switch (in_sizes[i]) {
      case 2217984:  pred[0] = p; break;
      case 554496:   pred[1] = p; break;
      case 138624:   pred[2] = p; break;
      case 19222528: emb[0] = p; break;
      case 4805632:  emb[1] = p; break;
      case 1201408:  emb[2] = p; break;
      default: break;
    }
  }
  char* ws = (char*)d_ws;
  float* ws_scores = (float*)(ws + OFF_SCORES);
  u64* ws_mask = (u64*)(ws + OFF_SCORES);     // aliases scores (scores dead after collect)
  u32* hist = (u32*)(ws + OFF_HIST);
  float* bufTs = (float*)(ws + OFF_BUFTS);    // aliases hist (hist dead after thresh)
  int* bufTi = (int*)(ws + OFF_BUFTI);
  float* bufGs = (float*)(ws + OFF_BUFGS);
  int* bufGi = (int*)(ws + OFF_BUFGI);
  u32* cntG = (u32*)(ws + OFF_CNTG);
  u32* cntT = (u32*)(ws + OFF_CNTT);
  int* thrT = (int*)(ws + OFF_THR);
  int* cnt = (int*)(ws + OFF_CNT);
  float* sel_score = (float*)(ws + OFF_SELS);
  int* sel_idx = (int*)(ws + OFF_SELI);
  float* ws_box = (float*)(ws + OFF_BOX);
  int* ws_src = (int*)(ws + OFF_SRC);

  hipMemsetAsync(hist, 0, 48 * 2048 * sizeof(u32), stream);
  score_kernel<<<dim3(1920), dim3(256), 0, stream>>>(pred[0], pred[1], pred[2], ws_scores, hist);
  thresh_kernel<<<dim3(48), dim3(256), 0, stream>>>(hist, thrT, cnt, cntG, cntT);
  collect_kernel<<<dim3(1920), dim3(256), 0, stream>>>(ws_scores, thrT, cntG, cntT, bufGs, bufGi, bufTs, bufTi);
  sort_kernel<<<dim3(48), dim3(1024), 0, stream>>>(bufGs, bufGi, bufTs, bufTi, cntG, cntT, cnt, sel_score, sel_idx);
  rank_kernel<<<dim3(48), dim3(512), 0, stream>>>(pred[0], pred[1], pred[2], sel_score, sel_idx, cnt, ws_box);
  mask_kernel<<<dim3(15, 16), dim3(256), 0, stream>>>(ws_box, cnt, ws_mask);
  scan_kernel<<<dim3(16), dim3(64), 0, stream>>>(ws_mask, cnt, ws_src);
  out_kernel<<<dim3(2000), dim3(256), 0, stream>>>(emb[0], emb[1], emb[2], ws_box, ws_src, sel_idx, (float*)d_out);
}